// Round 6
// baseline (153.744 us; speedup 1.0000x reference)
//
#include <hip/hip_runtime.h>
#include <math.h>

#define D 128
#define NPB 8
#define EPS1 (1.0f + 1e-6f)

__device__ __forceinline__ float sum16(float v) {
#pragma unroll
    for (int o = 8; o; o >>= 1) v += __shfl_xor(v, o, 64);
    return v;
}

// fast acosh for a >= 1+1e-6
__device__ __forceinline__ float facosh(float a) {
    return __logf(a + sqrtf(fmaxf(a * a - 1.0f, 0.0f)));
}

__device__ __forceinline__ void unpack8(const float4& a, const float4& b,
                                        float* d) {
    d[0] = a.x; d[1] = a.y; d[2] = a.z; d[3] = a.w;
    d[4] = b.x; d[5] = b.y; d[6] = b.z; d[7] = b.w;
}

// ---------------------------------------------------------------------------
// Kernel 1: per-node pre-processing. 256 threads = (j in [0,128)) x (kp in
// {0,1}). Elementwise phases: half kp owns nodes [kp*4, kp*4+4). Matmuls:
// thread (j,kp) computes partials over k in [kp*64,(kp+1)*64) for ALL 8
// nodes; partials merge through LDS psum. 1250 blocks x 4 waves = 5000 waves.
// ---------------------------------------------------------------------------
__device__ __forceinline__ void bsumH(float* v, float (*wred)[4], int lane,
                                      int wid, int kp) {
    __syncthreads();  // protect wred reuse
#pragma unroll
    for (int o = 32; o; o >>= 1)
#pragma unroll
        for (int nl = 0; nl < 4; nl++) v[nl] += __shfl_xor(v[nl], o, 64);
    if (lane == 0)
#pragma unroll
        for (int nl = 0; nl < 4; nl++) wred[wid][nl] = v[nl];
    __syncthreads();
#pragma unroll
    for (int nl = 0; nl < 4; nl++)
        v[nl] = wred[2 * kp][nl] + wred[2 * kp + 1][nl];
}

__global__ __launch_bounds__(256) void node_pre8(
    const float* __restrict__ h, const float* __restrict__ W,
    const float* __restrict__ bias, const float* __restrict__ att_w1,
    const float* __restrict__ att_b1, float* __restrict__ XQ,
    float* __restrict__ P_out, const int* __restrict__ row,
    int* __restrict__ cnt, int N, int E) {
    int i0 = blockIdx.x * NPB;
    int tid = threadIdx.x;
    int j = tid & 127, kp = tid >> 7;
    int lane = tid & 63, wid = tid >> 6;
    int nbase = kp * 4;
    __shared__ __align__(16) float t8[NPB][D];
    __shared__ float psumP[2][NPB][D];
    __shared__ float psumQ[2][NPB][D];
    __shared__ float wred[4][4];

    // logmap0(h) — own 4 nodes
    float hj[4];
#pragma unroll
    for (int nl = 0; nl < 4; nl++) {
        int gi = i0 + nbase + nl;
        hj[nl] = (gi < N) ? h[(size_t)gi * D + j] : 0.0f;
        t8[nbase + nl][j] = hj[nl];
    }
    __syncthreads();
    float tj[4];
#pragma unroll
    for (int nl = 0; nl < 4; nl++) {
        float h0 = fmaxf(t8[nbase + nl][0], EPS1);
        float fac = facosh(h0) * rsqrtf(h0 * h0 - 1.0f);
        tj[nl] = (j == 0) ? 0.0f : hj[nl] * fac;
    }
    __syncthreads();
#pragma unroll
    for (int nl = 0; nl < 4; nl++) t8[nbase + nl][j] = tj[nl];
    __syncthreads();

    // xt partial over this thread's k-half, all 8 nodes
    float xtp[NPB];
#pragma unroll
    for (int n = 0; n < NPB; n++) xtp[n] = 0.0f;
    int kbeg = kp * 64;
    for (int k0 = kbeg; k0 < kbeg + 64; k0 += 4) {
        float w0 = W[(k0 + 0) * D + j], w1 = W[(k0 + 1) * D + j];
        float w2 = W[(k0 + 2) * D + j], w3 = W[(k0 + 3) * D + j];
#pragma unroll
        for (int n = 0; n < NPB; n++) {
            float4 tv = *(const float4*)&t8[n][k0];
            xtp[n] = fmaf(tv.x, w0,
                          fmaf(tv.y, w1, fmaf(tv.z, w2, fmaf(tv.w, w3, xtp[n]))));
        }
    }
#pragma unroll
    for (int n = 0; n < NPB; n++) psumP[kp][n][j] = xtp[n];
    __syncthreads();
    float xt[4];
#pragma unroll
    for (int nl = 0; nl < 4; nl++) {
        int n = nbase + nl;
        xt[nl] = (j == 0) ? 0.0f : (psumP[0][n][j] + psumP[1][n][j]);
    }

    // x = expmap0([0, xt])
    float v4[4];
#pragma unroll
    for (int nl = 0; nl < 4; nl++) v4[nl] = xt[nl] * xt[nl];
    bsumH(v4, wred, lane, wid, kp);
    float xj[4];
#pragma unroll
    for (int nl = 0; nl < 4; nl++) {
        float nn = sqrtf(fmaxf(v4[nl], 1e-6f));
        float e = __expf(nn), ei = __fdividef(1.0f, e);
        float ch = 0.5f * (e + ei), sh = 0.5f * (e - ei);
        xj[nl] = (j == 0) ? ch : __fdividef(sh, nn) * xt[nl];
    }

    // b = transp0(x, [0,bias]); x = expmap(x, b)
    float vj = (j == 0) ? 0.0f : bias[j];
#pragma unroll
    for (int nl = 0; nl < 4; nl++) v4[nl] = xj[nl] * vj;
    bsumH(v4, wred, lane, wid, kp);
    __syncthreads();
#pragma unroll
    for (int nl = 0; nl < 4; nl++) t8[nbase + nl][j] = xj[nl];
    __syncthreads();
    float bj[4];
#pragma unroll
    for (int nl = 0; nl < 4; nl++) {
        float X0 = t8[nbase + nl][0];
        float coef = __fdividef(v4[nl], 1.0f + X0);
        bj[nl] = vj + coef * ((j == 0) ? (X0 + 1.0f) : xj[nl]);
    }
#pragma unroll
    for (int nl = 0; nl < 4; nl++)
        v4[nl] = (j == 0) ? -bj[nl] * bj[nl] : bj[nl] * bj[nl];
    bsumH(v4, wred, lane, wid, kp);
    float xnj[4];
#pragma unroll
    for (int nl = 0; nl < 4; nl++) {
        float nb = sqrtf(fmaxf(v4[nl], 1e-6f));
        float e = __expf(nb), ei = __fdividef(1.0f, e);
        float ch = 0.5f * (e + ei), sh = 0.5f * (e - ei);
        xnj[nl] = ch * xj[nl] + __fdividef(sh, nb) * bj[nl];
        int gi = i0 + nbase + nl;
        if (gi < N) XQ[(size_t)gi * 256 + j] = xnj[nl];
    }

    // x_tan = logmap0(x) -> t8
    __syncthreads();
#pragma unroll
    for (int nl = 0; nl < 4; nl++) t8[nbase + nl][j] = xnj[nl];
    __syncthreads();
    float xtj[4];
#pragma unroll
    for (int nl = 0; nl < 4; nl++) {
        float Y0 = fmaxf(t8[nbase + nl][0], EPS1);
        float f = facosh(Y0) * rsqrtf(Y0 * Y0 - 1.0f);
        xtj[nl] = (j == 0) ? 0.0f : xnj[nl] * f;
    }
    __syncthreads();
#pragma unroll
    for (int nl = 0; nl < 4; nl++) t8[nbase + nl][j] = xtj[nl];
    __syncthreads();

    // P/Q partials over k-half, all 8 nodes
    float pp[NPB], qq[NPB];
#pragma unroll
    for (int n = 0; n < NPB; n++) {
        pp[n] = 0.0f;
        qq[n] = 0.0f;
    }
    for (int k0 = kbeg; k0 < kbeg + 64; k0 += 4) {
        float a0 = att_w1[(k0 + 0) * D + j], a1 = att_w1[(k0 + 1) * D + j];
        float a2 = att_w1[(k0 + 2) * D + j], a3 = att_w1[(k0 + 3) * D + j];
        float c0 = att_w1[(D + k0 + 0) * D + j], c1 = att_w1[(D + k0 + 1) * D + j];
        float c2 = att_w1[(D + k0 + 2) * D + j], c3 = att_w1[(D + k0 + 3) * D + j];
#pragma unroll
        for (int n = 0; n < NPB; n++) {
            float4 tv = *(const float4*)&t8[n][k0];
            pp[n] = fmaf(tv.x, a0,
                         fmaf(tv.y, a1, fmaf(tv.z, a2, fmaf(tv.w, a3, pp[n]))));
            qq[n] = fmaf(tv.x, c0,
                         fmaf(tv.y, c1, fmaf(tv.z, c2, fmaf(tv.w, c3, qq[n]))));
        }
    }
#pragma unroll
    for (int n = 0; n < NPB; n++) {
        psumP[kp][n][j] = pp[n];
        psumQ[kp][n][j] = qq[n];
    }
    __syncthreads();
    float b1 = att_b1[j];
#pragma unroll
    for (int nl = 0; nl < 4; nl++) {
        int n = nbase + nl;
        int gi = i0 + n;
        if (gi < N) {
            P_out[(size_t)gi * D + j] = psumP[0][n][j] + psumP[1][n][j] + b1;
            XQ[(size_t)gi * 256 + 128 + j] = psumQ[0][n][j] + psumQ[1][n][j];
        }
    }

    // ---- folded histogram ----
    int gtid = blockIdx.x * 256 + tid;
    int tot = gridDim.x * 256;
    for (int e2 = gtid; e2 < E; e2 += tot) atomicAdd(&cnt[row[e2]], 1);
}

// ---------------------------------------------------------------------------
// CSR build: scan + scatter
// ---------------------------------------------------------------------------
__global__ __launch_bounds__(1024) void scan_kernel(const int* __restrict__ cnt,
                                                    int* __restrict__ off,
                                                    int* __restrict__ cursor,
                                                    int N) {
    __shared__ int wsum[16];
    __shared__ int carry_s;
    int tid = threadIdx.x, lane = tid & 63, wid = tid >> 6;
    if (tid == 0) carry_s = 0;
    __syncthreads();
    for (int base = 0; base < N; base += 1024) {
        int idx = base + tid;
        int v = (idx < N) ? cnt[idx] : 0;
        int orig = v;
#pragma unroll
        for (int o = 1; o < 64; o <<= 1) {
            int t = __shfl_up(v, o, 64);
            if (lane >= o) v += t;
        }
        if (lane == 63) wsum[wid] = v;
        __syncthreads();
        if (wid == 0 && lane < 16) {
            int w = wsum[lane];
#pragma unroll
            for (int o = 1; o < 16; o <<= 1) {
                int t = __shfl_up(w, o, 64);
                if (lane >= o) w += t;
            }
            wsum[lane] = w;
        }
        __syncthreads();
        int carry = carry_s;
        int wbase = (wid == 0) ? 0 : wsum[wid - 1];
        int excl = carry + wbase + v - orig;
        if (idx < N) {
            off[idx] = excl;
            cursor[idx] = excl;
        }
        __syncthreads();
        if (tid == 1023) carry_s = carry + wsum[15];
        __syncthreads();
    }
}

__global__ void scatter_kernel(const int* __restrict__ row,
                               const int* __restrict__ col,
                               const float* __restrict__ edge_attr,
                               const float* __restrict__ edge_mask,
                               int* __restrict__ cursor,
                               float4* __restrict__ rec, int E) {
    const float2* ea2 = (const float2*)edge_attr;
    for (int e = blockIdx.x * blockDim.x + threadIdx.x; e < E;
         e += gridDim.x * blockDim.x) {
        int r = row[e];
        int pos = atomicAdd(&cursor[r], 1);
        float2 a = ea2[e];
        rec[pos] = make_float4(__int_as_float(col[e]), a.x, a.y, edge_mask[e]);
    }
}

// ---------------------------------------------------------------------------
// Kernel D: edge aggregation. One WAVE per node, 4 chunks (one per 16-lane
// group). Each group processes edges in PAIRS with interleaved chains for
// 2x ILP; next pair prefetched during compute. No LDS, no atomics.
// ---------------------------------------------------------------------------
__global__ __launch_bounds__(256) void edge_agg(
    const float* __restrict__ XQ, const float* __restrict__ P,
    const float4* __restrict__ rec, const int* __restrict__ off,
    const int* __restrict__ cnt, const float* __restrict__ w1c,
    const float* __restrict__ att_w2, const float* __restrict__ att_b2,
    float* __restrict__ agg, int N) {
    int tid = threadIdx.x, lane = tid & 63;
    int sub = lane & 15, grp = lane >> 4;
    int i = blockIdx.x * 4 + (tid >> 6);  // wave = node
    bool valid = i < N;
    i = min(i, N - 1);
    int f4 = sub * 2;

    const float4* w4 = (const float4*)w1c;
    const float4* aw4 = (const float4*)att_w2;
    const float4* xq4r = (const float4*)(XQ + (size_t)i * 256);
    const float4* pr4 = (const float4*)(P + (size_t)i * D);
    float xr[8], pr[8], wa[8], wb[8], wg[8], w2v[8];
    unpack8(xq4r[f4], xq4r[f4 + 1], xr);
    unpack8(pr4[f4], pr4[f4 + 1], pr);
    unpack8(w4[f4], w4[f4 + 1], wa);
    unpack8(w4[32 + f4], w4[32 + f4 + 1], wb);
    unpack8(w4[64 + f4], w4[64 + f4 + 1], wg);
    unpack8(aw4[f4], aw4[f4 + 1], w2v);
    float b2 = att_b2[0];
    float xr0s = (sub == 0) ? -xr[0] : xr[0];

    float acc[8];
#pragma unroll
    for (int u = 0; u < 8; u++) acc[u] = 0.0f;

    int s = off[i], m = valid ? cnt[i] : 0;
    int clen = (m + 3) >> 2;  // wave-uniform chunk length
    int k0 = grp * clen;
    int len = min(m, k0 + clen) - k0;  // may be <=0 for trailing groups

    // interleaved 2-edge compute
    auto compute2 = [&](const float4& rc1, const float4& a0, const float4& a1,
                        const float4& a2, const float4& a3, bool act1,
                        const float4& rc2, const float4& b0, const float4& b1,
                        const float4& b2q, const float4& b3, bool act2) {
        float xc1[8], qc1[8], xc2[8], qc2[8];
        unpack8(a0, a1, xc1);
        unpack8(a2, a3, qc1);
        unpack8(b0, b1, xc2);
        unpack8(b2q, b3, qc2);
        float lin1 = xr0s * xc1[0];
        float lin2 = xr0s * xc2[0];
#pragma unroll
        for (int u = 1; u < 8; u++) {
            lin1 = fmaf(xr[u], xc1[u], lin1);
            lin2 = fmaf(xr[u], xc2[u], lin2);
        }
#pragma unroll
        for (int o = 8; o; o >>= 1) {
            lin1 += __shfl_xor(lin1, o, 64);
            lin2 += __shfl_xor(lin2, o, 64);
        }
        float alpha1 = fmaxf(-lin1, EPS1);
        float alpha2 = fmaxf(-lin2, EPS1);
        float a2m1 = fmaxf(fmaf(alpha1, alpha1, -1.0f), 1e-12f);
        float a2m2 = fmaxf(fmaf(alpha2, alpha2, -1.0f), 1e-12f);
        float rden1 = rsqrtf(a2m1);
        float rden2 = rsqrtf(a2m2);
        float geo1 = __logf(fmaf(a2m1, rden1, alpha1));
        float geo2 = __logf(fmaf(a2m2, rden2, alpha2));
        float lp1 = 0.0f, lp2 = 0.0f;
#pragma unroll
        for (int u = 0; u < 8; u++) {
            float hv1 = pr[u] + qc1[u] +
                        fmaf(rc1.y, wa[u], fmaf(rc1.z, wb[u], geo1 * wg[u]));
            float hv2 = pr[u] + qc2[u] +
                        fmaf(rc2.y, wa[u], fmaf(rc2.z, wb[u], geo2 * wg[u]));
            float sg1 = __fdividef(1.0f, 1.0f + __expf(-hv1));
            float sg2 = __fdividef(1.0f, 1.0f + __expf(-hv2));
            lp1 = fmaf(hv1 * sg1, w2v[u], lp1);
            lp2 = fmaf(hv2 * sg2, w2v[u], lp2);
        }
#pragma unroll
        for (int o = 8; o; o >>= 1) {
            lp1 += __shfl_xor(lp1, o, 64);
            lp2 += __shfl_xor(lp2, o, 64);
        }
        float w1 = act1 ? rc1.w : 0.0f;
        float w2 = act2 ? rc2.w : 0.0f;
        float att1 = w1 * __fdividef(1.0f, 1.0f + __expf(-(lp1 + b2)));
        float att2 = w2 * __fdividef(1.0f, 1.0f + __expf(-(lp2 + b2)));
        float sc1 = att1 * geo1 * rden1 * 1e-3f;
        float sc2 = att2 * geo2 * rden2 * 1e-3f;
#pragma unroll
        for (int u = 0; u < 8; u++) {
            acc[u] = fmaf(sc1, fmaf(-alpha1, xr[u], xc1[u]), acc[u]);
            acc[u] = fmaf(sc2, fmaf(-alpha2, xr[u], xc2[u]), acc[u]);
        }
    };

    float4 z = make_float4(__int_as_float(0), 0.0f, 0.0f, 0.0f);
    float4 rcA = z, rcB = z, rcC, rcD;
    if (len > 0) rcA = rec[s + k0];
    if (len > 1) rcB = rec[s + k0 + 1];
    const float4* pA = (const float4*)(XQ + (size_t)__float_as_int(rcA.x) * 256);
    const float4* pB = (const float4*)(XQ + (size_t)__float_as_int(rcB.x) * 256);
    float4 gA0 = pA[f4], gA1 = pA[f4 + 1], gA2 = pA[32 + f4],
           gA3 = pA[32 + f4 + 1];
    float4 gB0 = pB[f4], gB1 = pB[f4 + 1], gB2 = pB[32 + f4],
           gB3 = pB[32 + f4 + 1];

    for (int t = 0; t < clen; t += 2) {
        // prefetch pair (t+2, t+3)
        rcC = rcA;
        if (t + 2 < len) rcC = rec[s + k0 + t + 2];
        rcD = rcB;
        if (t + 3 < len) rcD = rec[s + k0 + t + 3];
        const float4* pC =
            (const float4*)(XQ + (size_t)__float_as_int(rcC.x) * 256);
        const float4* pD =
            (const float4*)(XQ + (size_t)__float_as_int(rcD.x) * 256);
        float4 gC0 = pC[f4], gC1 = pC[f4 + 1], gC2 = pC[32 + f4],
               gC3 = pC[32 + f4 + 1];
        float4 gD0 = pD[f4], gD1 = pD[f4 + 1], gD2 = pD[32 + f4],
               gD3 = pD[32 + f4 + 1];
        compute2(rcA, gA0, gA1, gA2, gA3, t < len, rcB, gB0, gB1, gB2, gB3,
                 t + 1 < len);
        rcA = rcC; rcB = rcD;
        gA0 = gC0; gA1 = gC1; gA2 = gC2; gA3 = gC3;
        gB0 = gD0; gB1 = gD1; gB2 = gD2; gB3 = gD3;
    }

    // merge the 4 chunk-partials within the wave
#pragma unroll
    for (int u = 0; u < 8; u++) {
        acc[u] += __shfl_xor(acc[u], 16, 64);
        acc[u] += __shfl_xor(acc[u], 32, 64);
    }
    if (valid && grp == 0) {
        float4* a4 = (float4*)(agg + (size_t)i * D);
        a4[f4] = make_float4(acc[0], acc[1], acc[2], acc[3]);
        a4[f4 + 1] = make_float4(acc[4], acc[5], acc[6], acc[7]);
    }
}

// ---------------------------------------------------------------------------
// Kernel E: per-node epilogue, 16-lane group per node, register-only.
// ---------------------------------------------------------------------------
__global__ __launch_bounds__(256) void node_post(
    const float* __restrict__ XQ, const float* __restrict__ agg,
    const float* __restrict__ gamma, const float* __restrict__ beta,
    float* __restrict__ out, int N) {
    int tid = threadIdx.x, lane = tid & 63;
    int sub = lane & 15;
    int i = blockIdx.x * 16 + (tid >> 4);
    bool valid = i < N;
    i = min(i, N - 1);
    int j8 = sub * 8, f4 = sub * 2;

    const float4* xq4r = (const float4*)(XQ + (size_t)i * 256);
    const float4* ag4 = (const float4*)(agg + (size_t)i * D);
    float xr[8], acc[8];
    unpack8(xq4r[f4], xq4r[f4 + 1], xr);
    unpack8(ag4[f4], ag4[f4 + 1], acc);

    float lxa_p = (sub == 0) ? -xr[0] * acc[0] : xr[0] * acc[0];
#pragma unroll
    for (int u = 1; u < 8; u++) lxa_p = fmaf(xr[u], acc[u], lxa_p);
    float lxa = sum16(lxa_p);
    float uj[8];
#pragma unroll
    for (int u = 0; u < 8; u++) uj[u] = fmaf(lxa, xr[u], acc[u]);
    float luu_p = (sub == 0) ? -uj[0] * uj[0] : uj[0] * uj[0];
#pragma unroll
    for (int u = 1; u < 8; u++) luu_p = fmaf(uj[u], uj[u], luu_p);
    float luu = sum16(luu_p);
    float nn = sqrtf(fmaxf(luu, 1e-6f));
    float e = __expf(nn), ei = __fdividef(1.0f, e);
    float ch = 0.5f * (e + ei), shv = __fdividef(0.5f * (e - ei), nn);
    float xn[8];
#pragma unroll
    for (int u = 0; u < 8; u++) xn[u] = ch * xr[u] + shv * uj[u];
    float X0 = __shfl(xn[0], lane & 48, 64);
    X0 = fmaxf(X0, EPS1);
    float fc = facosh(X0) * rsqrtf(X0 * X0 - 1.0f);
    float ht[8];
#pragma unroll
    for (int u = 0; u < 8; u++) ht[u] = xn[u] * fc;
    if (sub == 0) ht[0] = 0.0f;
    float mp = 0.0f;
#pragma unroll
    for (int u = 0; u < 8; u++) mp += ht[u];
    float mean = sum16(mp) * (1.0f / 127.0f);
    float diff[8];
#pragma unroll
    for (int u = 0; u < 8; u++) diff[u] = ht[u] - mean;
    if (sub == 0) diff[0] = 0.0f;
    float vp = 0.0f;
#pragma unroll
    for (int u = 0; u < 8; u++) vp = fmaf(diff[u], diff[u], vp);
    float var = sum16(vp) * (1.0f / 127.0f);
    float rstd = rsqrtf(var + 1e-5f);
    float sp[8];
#pragma unroll
    for (int u = 0; u < 8; u++) {
        int j = j8 + u;
        sp[u] = (j > 0) ? fmaf(diff[u] * rstd, gamma[j - 1], beta[j - 1]) : 0.0f;
    }
    float n2p = 0.0f;
#pragma unroll
    for (int u = 0; u < 8; u++) n2p = fmaf(sp[u], sp[u], n2p);
    float n2 = sqrtf(fmaxf(sum16(n2p), 1e-6f));
    e = __expf(n2);
    ei = __fdividef(1.0f, e);
    float y0 = 0.5f * (e + ei), sh2 = __fdividef(0.5f * (e - ei), n2);
    float yj[8];
#pragma unroll
    for (int u = 0; u < 8; u++) yj[u] = sh2 * sp[u];
    if (sub == 0) yj[0] = y0;
    float y0c = fmaxf(y0, EPS1);
    float f3 = facosh(y0c) * rsqrtf(y0c * y0c - 1.0f);
    float sj[8];
#pragma unroll
    for (int u = 0; u < 8; u++) {
        float lj = yj[u] * f3;
        sj[u] = __fdividef(lj, 1.0f + __expf(-lj));
    }
    if (sub == 0) sj[0] = 0.0f;
    float n3p = 0.0f;
#pragma unroll
    for (int u = 0; u < 8; u++) n3p = fmaf(sj[u], sj[u], n3p);
    float n3 = sqrtf(fmaxf(sum16(n3p), 1e-6f));
    e = __expf(n3);
    ei = __fdividef(1.0f, e);
    float o0 = 0.5f * (e + ei), sh3 = __fdividef(0.5f * (e - ei), n3);
    float ov[8];
#pragma unroll
    for (int u = 0; u < 8; u++) ov[u] = sh3 * sj[u];
    if (sub == 0) ov[0] = o0;
    if (valid) {
        float4* o4 = (float4*)(out + (size_t)i * D);
        o4[f4] = make_float4(ov[0], ov[1], ov[2], ov[3]);
        o4[f4 + 1] = make_float4(ov[4], ov[5], ov[6], ov[7]);
    }
}

extern "C" void kernel_launch(void* const* d_in, const int* in_sizes, int n_in,
                              void* d_out, int out_size, void* d_ws,
                              size_t ws_size, hipStream_t stream) {
    const float* h = (const float*)d_in[0];
    const float* edge_attr = (const float*)d_in[1];
    const int* row = (const int*)d_in[2];
    const int* col = (const int*)d_in[3];
    const float* edge_mask = (const float*)d_in[5];
    const float* W = (const float*)d_in[6];
    const float* bias = (const float*)d_in[7];
    const float* att_w1 = (const float*)d_in[8];
    const float* att_b1 = (const float*)d_in[9];
    const float* att_w2 = (const float*)d_in[10];
    const float* att_b2 = (const float*)d_in[11];
    const float* ln_g = (const float*)d_in[12];
    const float* ln_b = (const float*)d_in[13];

    int N = in_sizes[0] / D;
    int E = in_sizes[2];

    float* XQ = (float*)d_ws;                       // N*256
    float* Pbuf = XQ + (size_t)N * 256;             // N*128
    float4* rec = (float4*)(Pbuf + (size_t)N * D);  // E
    int* cnt = (int*)(rec + E);
    int* off = cnt + N;
    int* cur = off + N;
    float* aggb = (float*)(cur + N);                // N*128

    hipMemsetAsync(cnt, 0, N * sizeof(int), stream);
    node_pre8<<<(N + NPB - 1) / NPB, 256, 0, stream>>>(
        h, W, bias, att_w1, att_b1, XQ, Pbuf, row, cnt, N, E);
    scan_kernel<<<1, 1024, 0, stream>>>(cnt, off, cur, N);
    scatter_kernel<<<640, 256, 0, stream>>>(row, col, edge_attr, edge_mask,
                                            cur, rec, E);
    edge_agg<<<(N + 3) / 4, 256, 0, stream>>>(XQ, Pbuf, rec, off, cnt,
                                              att_w1 + 256 * D, att_w2, att_b2,
                                              aggb, N);
    node_post<<<(N + 15) / 16, 256, 0, stream>>>(XQ, aggb, ln_g, ln_b,
                                                 (float*)d_out, N);
}

// Round 7
// 146.443 us; speedup vs baseline: 1.0499x; 1.0499x over previous
//
#include <hip/hip_runtime.h>
#include <math.h>

#define D 128
#define NPB 8
#define EPS1 (1.0f + 1e-6f)

// ---- DPP row_ror sum over each 16-lane row: all lanes get the total ----
__device__ __forceinline__ float dpp_rsum16(float v) {
    v += __int_as_float(__builtin_amdgcn_update_dpp(
        0, __float_as_int(v), 0x121, 0xf, 0xf, true));  // ror:1
    v += __int_as_float(__builtin_amdgcn_update_dpp(
        0, __float_as_int(v), 0x122, 0xf, 0xf, true));  // ror:2
    v += __int_as_float(__builtin_amdgcn_update_dpp(
        0, __float_as_int(v), 0x124, 0xf, 0xf, true));  // ror:4
    v += __int_as_float(__builtin_amdgcn_update_dpp(
        0, __float_as_int(v), 0x128, 0xf, 0xf, true));  // ror:8
    return v;
}

// fast acosh for a >= 1+1e-6
__device__ __forceinline__ float facosh(float a) {
    return __logf(a + sqrtf(fmaxf(a * a - 1.0f, 0.0f)));
}

__device__ __forceinline__ void unpack8(const float4& a, const float4& b,
                                        float* d) {
    d[0] = a.x; d[1] = a.y; d[2] = a.z; d[3] = a.w;
    d[4] = b.x; d[5] = b.y; d[6] = b.z; d[7] = b.w;
}

// ---------------------------------------------------------------------------
// Kernel 1: per-node pre-processing. 256 threads = (j in [0,128)) x (kp in
// {0,1}). Elementwise phases: half kp owns nodes [kp*4, kp*4+4). Matmuls:
// thread (j,kp) computes partials over k in [kp*64,(kp+1)*64) for ALL 8
// nodes; partials merge through LDS psum.
// ---------------------------------------------------------------------------
__device__ __forceinline__ void bsumH(float* v, float (*wred)[4], int lane,
                                      int wid, int kp) {
    __syncthreads();  // protect wred reuse
#pragma unroll
    for (int o = 32; o; o >>= 1)
#pragma unroll
        for (int nl = 0; nl < 4; nl++) v[nl] += __shfl_xor(v[nl], o, 64);
    if (lane == 0)
#pragma unroll
        for (int nl = 0; nl < 4; nl++) wred[wid][nl] = v[nl];
    __syncthreads();
#pragma unroll
    for (int nl = 0; nl < 4; nl++)
        v[nl] = wred[2 * kp][nl] + wred[2 * kp + 1][nl];
}

__global__ __launch_bounds__(256) void node_pre8(
    const float* __restrict__ h, const float* __restrict__ W,
    const float* __restrict__ bias, const float* __restrict__ att_w1,
    const float* __restrict__ att_b1, float* __restrict__ XQ,
    float* __restrict__ P_out, const int* __restrict__ row,
    int* __restrict__ cnt, int N, int E) {
    int i0 = blockIdx.x * NPB;
    int tid = threadIdx.x;
    int j = tid & 127, kp = tid >> 7;
    int lane = tid & 63, wid = tid >> 6;
    int nbase = kp * 4;
    __shared__ __align__(16) float t8[NPB][D];
    __shared__ float psumP[2][NPB][D];
    __shared__ float psumQ[2][NPB][D];
    __shared__ float wred[4][4];

    // logmap0(h) — own 4 nodes
    float hj[4];
#pragma unroll
    for (int nl = 0; nl < 4; nl++) {
        int gi = i0 + nbase + nl;
        hj[nl] = (gi < N) ? h[(size_t)gi * D + j] : 0.0f;
        t8[nbase + nl][j] = hj[nl];
    }
    __syncthreads();
    float tj[4];
#pragma unroll
    for (int nl = 0; nl < 4; nl++) {
        float h0 = fmaxf(t8[nbase + nl][0], EPS1);
        float fac = facosh(h0) * rsqrtf(h0 * h0 - 1.0f);
        tj[nl] = (j == 0) ? 0.0f : hj[nl] * fac;
    }
    __syncthreads();
#pragma unroll
    for (int nl = 0; nl < 4; nl++) t8[nbase + nl][j] = tj[nl];
    __syncthreads();

    // xt partial over this thread's k-half, all 8 nodes
    float xtp[NPB];
#pragma unroll
    for (int n = 0; n < NPB; n++) xtp[n] = 0.0f;
    int kbeg = kp * 64;
    for (int k0 = kbeg; k0 < kbeg + 64; k0 += 4) {
        float w0 = W[(k0 + 0) * D + j], w1 = W[(k0 + 1) * D + j];
        float w2 = W[(k0 + 2) * D + j], w3 = W[(k0 + 3) * D + j];
#pragma unroll
        for (int n = 0; n < NPB; n++) {
            float4 tv = *(const float4*)&t8[n][k0];
            xtp[n] = fmaf(tv.x, w0,
                          fmaf(tv.y, w1, fmaf(tv.z, w2, fmaf(tv.w, w3, xtp[n]))));
        }
    }
#pragma unroll
    for (int n = 0; n < NPB; n++) psumP[kp][n][j] = xtp[n];
    __syncthreads();
    float xt[4];
#pragma unroll
    for (int nl = 0; nl < 4; nl++) {
        int n = nbase + nl;
        xt[nl] = (j == 0) ? 0.0f : (psumP[0][n][j] + psumP[1][n][j]);
    }

    // x = expmap0([0, xt])
    float v4[4];
#pragma unroll
    for (int nl = 0; nl < 4; nl++) v4[nl] = xt[nl] * xt[nl];
    bsumH(v4, wred, lane, wid, kp);
    float xj[4];
#pragma unroll
    for (int nl = 0; nl < 4; nl++) {
        float nn = sqrtf(fmaxf(v4[nl], 1e-6f));
        float e = __expf(nn), ei = __fdividef(1.0f, e);
        float ch = 0.5f * (e + ei), sh = 0.5f * (e - ei);
        xj[nl] = (j == 0) ? ch : __fdividef(sh, nn) * xt[nl];
    }

    // b = transp0(x, [0,bias]); x = expmap(x, b)
    float vj = (j == 0) ? 0.0f : bias[j];
#pragma unroll
    for (int nl = 0; nl < 4; nl++) v4[nl] = xj[nl] * vj;
    bsumH(v4, wred, lane, wid, kp);
    __syncthreads();
#pragma unroll
    for (int nl = 0; nl < 4; nl++) t8[nbase + nl][j] = xj[nl];
    __syncthreads();
    float bj[4];
#pragma unroll
    for (int nl = 0; nl < 4; nl++) {
        float X0 = t8[nbase + nl][0];
        float coef = __fdividef(v4[nl], 1.0f + X0);
        bj[nl] = vj + coef * ((j == 0) ? (X0 + 1.0f) : xj[nl]);
    }
#pragma unroll
    for (int nl = 0; nl < 4; nl++)
        v4[nl] = (j == 0) ? -bj[nl] * bj[nl] : bj[nl] * bj[nl];
    bsumH(v4, wred, lane, wid, kp);
    float xnj[4];
#pragma unroll
    for (int nl = 0; nl < 4; nl++) {
        float nb = sqrtf(fmaxf(v4[nl], 1e-6f));
        float e = __expf(nb), ei = __fdividef(1.0f, e);
        float ch = 0.5f * (e + ei), sh = 0.5f * (e - ei);
        xnj[nl] = ch * xj[nl] + __fdividef(sh, nb) * bj[nl];
        int gi = i0 + nbase + nl;
        if (gi < N) XQ[(size_t)gi * 256 + j] = xnj[nl];
    }

    // x_tan = logmap0(x) -> t8
    __syncthreads();
#pragma unroll
    for (int nl = 0; nl < 4; nl++) t8[nbase + nl][j] = xnj[nl];
    __syncthreads();
    float xtj[4];
#pragma unroll
    for (int nl = 0; nl < 4; nl++) {
        float Y0 = fmaxf(t8[nbase + nl][0], EPS1);
        float f = facosh(Y0) * rsqrtf(Y0 * Y0 - 1.0f);
        xtj[nl] = (j == 0) ? 0.0f : xnj[nl] * f;
    }
    __syncthreads();
#pragma unroll
    for (int nl = 0; nl < 4; nl++) t8[nbase + nl][j] = xtj[nl];
    __syncthreads();

    // P/Q partials over k-half, all 8 nodes
    float pp[NPB], qq[NPB];
#pragma unroll
    for (int n = 0; n < NPB; n++) {
        pp[n] = 0.0f;
        qq[n] = 0.0f;
    }
    for (int k0 = kbeg; k0 < kbeg + 64; k0 += 4) {
        float a0 = att_w1[(k0 + 0) * D + j], a1 = att_w1[(k0 + 1) * D + j];
        float a2 = att_w1[(k0 + 2) * D + j], a3 = att_w1[(k0 + 3) * D + j];
        float c0 = att_w1[(D + k0 + 0) * D + j], c1 = att_w1[(D + k0 + 1) * D + j];
        float c2 = att_w1[(D + k0 + 2) * D + j], c3 = att_w1[(D + k0 + 3) * D + j];
#pragma unroll
        for (int n = 0; n < NPB; n++) {
            float4 tv = *(const float4*)&t8[n][k0];
            pp[n] = fmaf(tv.x, a0,
                         fmaf(tv.y, a1, fmaf(tv.z, a2, fmaf(tv.w, a3, pp[n]))));
            qq[n] = fmaf(tv.x, c0,
                         fmaf(tv.y, c1, fmaf(tv.z, c2, fmaf(tv.w, c3, qq[n]))));
        }
    }
#pragma unroll
    for (int n = 0; n < NPB; n++) {
        psumP[kp][n][j] = pp[n];
        psumQ[kp][n][j] = qq[n];
    }
    __syncthreads();
    float b1 = att_b1[j];
#pragma unroll
    for (int nl = 0; nl < 4; nl++) {
        int n = nbase + nl;
        int gi = i0 + n;
        if (gi < N) {
            P_out[(size_t)gi * D + j] = psumP[0][n][j] + psumP[1][n][j] + b1;
            XQ[(size_t)gi * 256 + 128 + j] = psumQ[0][n][j] + psumQ[1][n][j];
        }
    }

    // ---- folded histogram ----
    int gtid = blockIdx.x * 256 + tid;
    int tot = gridDim.x * 256;
    for (int e2 = gtid; e2 < E; e2 += tot) atomicAdd(&cnt[row[e2]], 1);
}

// ---------------------------------------------------------------------------
// CSR build: scan + scatter
// ---------------------------------------------------------------------------
__global__ __launch_bounds__(1024) void scan_kernel(const int* __restrict__ cnt,
                                                    int* __restrict__ off,
                                                    int* __restrict__ cursor,
                                                    int N) {
    __shared__ int wsum[16];
    __shared__ int carry_s;
    int tid = threadIdx.x, lane = tid & 63, wid = tid >> 6;
    if (tid == 0) carry_s = 0;
    __syncthreads();
    for (int base = 0; base < N; base += 1024) {
        int idx = base + tid;
        int v = (idx < N) ? cnt[idx] : 0;
        int orig = v;
#pragma unroll
        for (int o = 1; o < 64; o <<= 1) {
            int t = __shfl_up(v, o, 64);
            if (lane >= o) v += t;
        }
        if (lane == 63) wsum[wid] = v;
        __syncthreads();
        if (wid == 0 && lane < 16) {
            int w = wsum[lane];
#pragma unroll
            for (int o = 1; o < 16; o <<= 1) {
                int t = __shfl_up(w, o, 64);
                if (lane >= o) w += t;
            }
            wsum[lane] = w;
        }
        __syncthreads();
        int carry = carry_s;
        int wbase = (wid == 0) ? 0 : wsum[wid - 1];
        int excl = carry + wbase + v - orig;
        if (idx < N) {
            off[idx] = excl;
            cursor[idx] = excl;
        }
        __syncthreads();
        if (tid == 1023) carry_s = carry + wsum[15];
        __syncthreads();
    }
}

__global__ void scatter_kernel(const int* __restrict__ row,
                               const int* __restrict__ col,
                               const float* __restrict__ edge_attr,
                               const float* __restrict__ edge_mask,
                               int* __restrict__ cursor,
                               float4* __restrict__ rec, int E) {
    const float2* ea2 = (const float2*)edge_attr;
    for (int e = blockIdx.x * blockDim.x + threadIdx.x; e < E;
         e += gridDim.x * blockDim.x) {
        int r = row[e];
        int pos = atomicAdd(&cursor[r], 1);
        float2 a = ea2[e];
        rec[pos] = make_float4(__int_as_float(col[e]), a.x, a.y, edge_mask[e]);
    }
}

// ---------------------------------------------------------------------------
// Kernel D: edge aggregation + fused epilogue. One WAVE per node, 4 chunks
// (one per 16-lane group). All intra-group reductions via DPP row_ror adds
// (VALU pipe, no LDS ops). After the wave merge, every lane holds the full
// accumulator; the node epilogue runs in-register and group 0 stores.
// ---------------------------------------------------------------------------
__global__ __launch_bounds__(256) void edge_agg(
    const float* __restrict__ XQ, const float* __restrict__ P,
    const float4* __restrict__ rec, const int* __restrict__ off,
    const int* __restrict__ cnt, const float* __restrict__ w1c,
    const float* __restrict__ att_w2, const float* __restrict__ att_b2,
    const float* __restrict__ gamma, const float* __restrict__ beta,
    float* __restrict__ out, int N) {
    int tid = threadIdx.x, lane = tid & 63;
    int sub = lane & 15, grp = lane >> 4;
    int i = blockIdx.x * 4 + (tid >> 6);  // wave = node
    bool valid = i < N;
    i = min(i, N - 1);
    int j8 = sub * 8, f4 = sub * 2;

    const float4* w4 = (const float4*)w1c;
    const float4* aw4 = (const float4*)att_w2;
    const float4* xq4r = (const float4*)(XQ + (size_t)i * 256);
    const float4* pr4 = (const float4*)(P + (size_t)i * D);
    float xr[8], pr[8], wa[8], wb[8], wg[8], w2v[8];
    unpack8(xq4r[f4], xq4r[f4 + 1], xr);
    unpack8(pr4[f4], pr4[f4 + 1], pr);
    unpack8(w4[f4], w4[f4 + 1], wa);
    unpack8(w4[32 + f4], w4[32 + f4 + 1], wb);
    unpack8(w4[64 + f4], w4[64 + f4 + 1], wg);
    unpack8(aw4[f4], aw4[f4 + 1], w2v);
    float b2 = att_b2[0];
    float xr0s = (sub == 0) ? -xr[0] : xr[0];

    float acc[8];
#pragma unroll
    for (int u = 0; u < 8; u++) acc[u] = 0.0f;

    int s = off[i], m = valid ? cnt[i] : 0;
    int clen = (m + 3) >> 2;           // wave-uniform chunk length
    int k0 = grp * clen;
    int len = min(m, k0 + clen) - k0;  // may be <=0 for trailing groups

    auto compute = [&](const float4& rc, const float4& g0, const float4& g1,
                       const float4& g2, const float4& g3, bool act) {
        float xc[8], qc[8];
        unpack8(g0, g1, xc);
        unpack8(g2, g3, qc);
        float lin = xr0s * xc[0];
#pragma unroll
        for (int u = 1; u < 8; u++) lin = fmaf(xr[u], xc[u], lin);
        lin = dpp_rsum16(lin);
        float alpha = fmaxf(-lin, EPS1);
        float a2m = fmaxf(fmaf(alpha, alpha, -1.0f), 1e-12f);
        float rden = rsqrtf(a2m);
        float geo = __logf(fmaf(a2m, rden, alpha));  // acosh(alpha)
        float lp = 0.0f;
#pragma unroll
        for (int u = 0; u < 8; u++) {
            float hv = pr[u] + qc[u] +
                       fmaf(rc.y, wa[u], fmaf(rc.z, wb[u], geo * wg[u]));
            float sig = __fdividef(1.0f, 1.0f + __expf(-hv));
            lp = fmaf(hv * sig, w2v[u], lp);  // silu(h)*w2
        }
        lp = dpp_rsum16(lp);
        float w = act ? rc.w : 0.0f;
        float att = w * __fdividef(1.0f, 1.0f + __expf(-(lp + b2)));
        float scale = att * geo * rden * 1e-3f;
#pragma unroll
        for (int u = 0; u < 8; u++)
            acc[u] = fmaf(scale, fmaf(-alpha, xr[u], xc[u]), acc[u]);
    };

    // ---- software-pipelined chunk loop (depth 2), wave-uniform bound ----
    float4 rcA = make_float4(__int_as_float(0), 0.0f, 0.0f, 0.0f), rcB;
    if (len > 0) rcA = rec[s + k0];
    const float4* pA =
        (const float4*)(XQ + (size_t)__float_as_int(rcA.x) * 256);
    float4 gA0 = pA[f4], gA1 = pA[f4 + 1], gA2 = pA[32 + f4],
           gA3 = pA[32 + f4 + 1];
    float4 gB0, gB1, gB2, gB3;

    for (int t = 0; t < clen; t += 2) {
        rcB = rcA;
        if (t + 1 < len) rcB = rec[s + k0 + t + 1];
        const float4* pB =
            (const float4*)(XQ + (size_t)__float_as_int(rcB.x) * 256);
        gB0 = pB[f4]; gB1 = pB[f4 + 1]; gB2 = pB[32 + f4]; gB3 = pB[32 + f4 + 1];
        compute(rcA, gA0, gA1, gA2, gA3, t < len);
        rcA = rcB;
        if (t + 2 < len) rcA = rec[s + k0 + t + 2];
        const float4* pN =
            (const float4*)(XQ + (size_t)__float_as_int(rcA.x) * 256);
        gA0 = pN[f4]; gA1 = pN[f4 + 1]; gA2 = pN[32 + f4]; gA3 = pN[32 + f4 + 1];
        compute(rcB, gB0, gB1, gB2, gB3, t + 1 < len);
    }

    // ---- merge the 4 chunk-partials: every lane gets the full sum ----
#pragma unroll
    for (int u = 0; u < 8; u++) {
        acc[u] += __shfl_xor(acc[u], 16, 64);
        acc[u] += __shfl_xor(acc[u], 32, 64);
    }

    // ---- fused epilogue (all lanes compute; grp 0 stores) ----
    float lxa_p = (sub == 0) ? -xr[0] * acc[0] : xr[0] * acc[0];
#pragma unroll
    for (int u = 1; u < 8; u++) lxa_p = fmaf(xr[u], acc[u], lxa_p);
    float lxa = dpp_rsum16(lxa_p);
    float uj[8];
#pragma unroll
    for (int u = 0; u < 8; u++) uj[u] = fmaf(lxa, xr[u], acc[u]);
    float luu_p = (sub == 0) ? -uj[0] * uj[0] : uj[0] * uj[0];
#pragma unroll
    for (int u = 1; u < 8; u++) luu_p = fmaf(uj[u], uj[u], luu_p);
    float luu = dpp_rsum16(luu_p);
    float nn = sqrtf(fmaxf(luu, 1e-6f));
    float e = __expf(nn), ei = __fdividef(1.0f, e);
    float ch = 0.5f * (e + ei), shv = __fdividef(0.5f * (e - ei), nn);
    float xn[8];
#pragma unroll
    for (int u = 0; u < 8; u++) xn[u] = ch * xr[u] + shv * uj[u];
    float X0 = __shfl(xn[0], lane & 48, 64);  // group-base lane's j=0 comp
    X0 = fmaxf(X0, EPS1);
    float fc = facosh(X0) * rsqrtf(X0 * X0 - 1.0f);
    float ht[8];
#pragma unroll
    for (int u = 0; u < 8; u++) ht[u] = xn[u] * fc;
    if (sub == 0) ht[0] = 0.0f;
    float mp = 0.0f;
#pragma unroll
    for (int u = 0; u < 8; u++) mp += ht[u];
    float mean = dpp_rsum16(mp) * (1.0f / 127.0f);
    float diff[8];
#pragma unroll
    for (int u = 0; u < 8; u++) diff[u] = ht[u] - mean;
    if (sub == 0) diff[0] = 0.0f;
    float vp = 0.0f;
#pragma unroll
    for (int u = 0; u < 8; u++) vp = fmaf(diff[u], diff[u], vp);
    float var = dpp_rsum16(vp) * (1.0f / 127.0f);
    float rstd = rsqrtf(var + 1e-5f);
    float sp[8];
#pragma unroll
    for (int u = 0; u < 8; u++) {
        int j = j8 + u;
        sp[u] = (j > 0) ? fmaf(diff[u] * rstd, gamma[j - 1], beta[j - 1]) : 0.0f;
    }
    float n2p = 0.0f;
#pragma unroll
    for (int u = 0; u < 8; u++) n2p = fmaf(sp[u], sp[u], n2p);
    float n2 = sqrtf(fmaxf(dpp_rsum16(n2p), 1e-6f));
    e = __expf(n2);
    ei = __fdividef(1.0f, e);
    float y0 = 0.5f * (e + ei), sh2 = __fdividef(0.5f * (e - ei), n2);
    float yj[8];
#pragma unroll
    for (int u = 0; u < 8; u++) yj[u] = sh2 * sp[u];
    if (sub == 0) yj[0] = y0;
    float y0c = fmaxf(y0, EPS1);
    float f3 = facosh(y0c) * rsqrtf(y0c * y0c - 1.0f);
    float sj[8];
#pragma unroll
    for (int u = 0; u < 8; u++) {
        float lj = yj[u] * f3;
        sj[u] = __fdividef(lj, 1.0f + __expf(-lj));
    }
    if (sub == 0) sj[0] = 0.0f;
    float n3p = 0.0f;
#pragma unroll
    for (int u = 0; u < 8; u++) n3p = fmaf(sj[u], sj[u], n3p);
    float n3 = sqrtf(fmaxf(dpp_rsum16(n3p), 1e-6f));
    e = __expf(n3);
    ei = __fdividef(1.0f, e);
    float o0 = 0.5f * (e + ei), sh3 = __fdividef(0.5f * (e - ei), n3);
    float ov[8];
#pragma unroll
    for (int u = 0; u < 8; u++) ov[u] = sh3 * sj[u];
    if (sub == 0) ov[0] = o0;
    if (valid && grp == 0) {
        float4* o4 = (float4*)(out + (size_t)i * D);
        o4[f4] = make_float4(ov[0], ov[1], ov[2], ov[3]);
        o4[f4 + 1] = make_float4(ov[4], ov[5], ov[6], ov[7]);
    }
}

extern "C" void kernel_launch(void* const* d_in, const int* in_sizes, int n_in,
                              void* d_out, int out_size, void* d_ws,
                              size_t ws_size, hipStream_t stream) {
    const float* h = (const float*)d_in[0];
    const float* edge_attr = (const float*)d_in[1];
    const int* row = (const int*)d_in[2];
    const int* col = (const int*)d_in[3];
    const float* edge_mask = (const float*)d_in[5];
    const float* W = (const float*)d_in[6];
    const float* bias = (const float*)d_in[7];
    const float* att_w1 = (const float*)d_in[8];
    const float* att_b1 = (const float*)d_in[9];
    const float* att_w2 = (const float*)d_in[10];
    const float* att_b2 = (const float*)d_in[11];
    const float* ln_g = (const float*)d_in[12];
    const float* ln_b = (const float*)d_in[13];

    int N = in_sizes[0] / D;
    int E = in_sizes[2];

    float* XQ = (float*)d_ws;                       // N*256
    float* Pbuf = XQ + (size_t)N * 256;             // N*128
    float4* rec = (float4*)(Pbuf + (size_t)N * D);  // E
    int* cnt = (int*)(rec + E);
    int* off = cnt + N;
    int* cur = off + N;

    hipMemsetAsync(cnt, 0, N * sizeof(int), stream);
    node_pre8<<<(N + NPB - 1) / NPB, 256, 0, stream>>>(
        h, W, bias, att_w1, att_b1, XQ, Pbuf, row, cnt, N, E);
    scan_kernel<<<1, 1024, 0, stream>>>(cnt, off, cur, N);
    scatter_kernel<<<640, 256, 0, stream>>>(row, col, edge_attr, edge_mask,
                                            cur, rec, E);
    edge_agg<<<(N + 3) / 4, 256, 0, stream>>>(XQ, Pbuf, rec, off, cnt,
                                              att_w1 + 256 * D, att_w2, att_b2,
                                              ln_g, ln_b, (float*)d_out, N);
}